// Round 1
// baseline (207.401 us; speedup 1.0000x reference)
//
#include <hip/hip_runtime.h>

#define NDATA 100000
#define KP1 16385            // NCE_K + 1
#define BSZ 64
#define PTOT (BSZ * KP1)     // 1,048,640
#define NCHUNKS 6250         // NDATA / 16 (exact, no remainder)
#define INV_T (1.0f / 0.07f)

typedef short short8 __attribute__((ext_vector_type(8)));
typedef float f32x4 __attribute__((ext_vector_type(4)));

__device__ __forceinline__ float wave_reduce64(float v) {
    #pragma unroll
    for (int off = 32; off >= 1; off >>= 1) v += __shfl_xor(v, off);
    return v;
}

__device__ __forceinline__ unsigned short f2bf(float f) {
    unsigned u = __float_as_uint(f);
    u += 0x7FFFu + ((u >> 16) & 1u);   // round-to-nearest-even
    return (unsigned short)(u >> 16);
}

__device__ __forceinline__ short8 pack_bf16(float4 lo, float4 hi) {
    short8 r;
    r[0] = (short)f2bf(lo.x); r[1] = (short)f2bf(lo.y);
    r[2] = (short)f2bf(lo.z); r[3] = (short)f2bf(lo.w);
    r[4] = (short)f2bf(hi.x); r[5] = (short)f2bf(hi.y);
    r[6] = (short)f2bf(hi.z); r[7] = (short)f2bf(hi.w);
    return r;
}

__device__ __forceinline__ float dot4(float4 a, float4 b, float acc) {
    acc = fmaf(a.x, b.x, acc);
    acc = fmaf(a.y, b.y, acc);
    acc = fmaf(a.z, b.z, acc);
    return fmaf(a.w, b.w, acc);
}

// ---------------- embed: raw dots + norm^2 accumulation ----------------------
// grid (8 d-tiles, 32 b-pairs); W demand ~49 MB (L2/L3-cached).
__global__ __launch_bounds__(256) void embed_kernel(
    const float* __restrict__ fs, const float* __restrict__ ft,
    const float* __restrict__ Ws, const float* __restrict__ bs,
    const float* __restrict__ Wt, const float* __restrict__ bt,
    float* __restrict__ vraw_s, float* __restrict__ vraw_t,
    float* __restrict__ n2s, float* __restrict__ n2t)
{
    __shared__ __align__(16) float4 FS[512];    // 2 b x 1024 f
    __shared__ __align__(16) float4 FT[1024];   // 2 b x 2048 f

    const int t  = threadIdx.x;
    const int dt = blockIdx.x;        // dims dt*16 .. dt*16+15
    const int b0 = blockIdx.y * 2;

    for (int q = t; q < 512; q += 256) {
        const int b = q >> 8, i = q & 255;
        FS[q] = ((const float4*)(fs + (size_t)(b0 + b) * 1024))[i];
    }
    for (int q = t; q < 1024; q += 256) {
        const int b = q >> 9, i = q & 511;
        FT[q] = ((const float4*)(ft + (size_t)(b0 + b) * 2048))[i];
    }
    __syncthreads();

    const int w = t >> 6, lane = t & 63;
    float ps0 = 0.0f, ps1 = 0.0f, pt0 = 0.0f, pt1 = 0.0f;

    #pragma unroll
    for (int r = 0; r < 4; ++r) {                 // s-side: 4 dims per wave
        const int d = dt * 16 + w * 4 + r;
        const float4* wrow = (const float4*)(Ws + (size_t)d * 1024);
        float a0 = 0.0f, a1 = 0.0f;
        #pragma unroll
        for (int i = 0; i < 4; ++i) {
            const float4 wv = wrow[i * 64 + lane];
            a0 = dot4(wv, FS[i * 64 + lane], a0);
            a1 = dot4(wv, FS[256 + i * 64 + lane], a1);
        }
        a0 = wave_reduce64(a0) + bs[d];
        a1 = wave_reduce64(a1) + bs[d];
        ps0 = fmaf(a0, a0, ps0);
        ps1 = fmaf(a1, a1, ps1);
        if (lane == 0) {
            vraw_s[(size_t)b0 * 128 + d]       = a0;
            vraw_s[(size_t)(b0 + 1) * 128 + d] = a1;
        }
    }
    #pragma unroll
    for (int r = 0; r < 4; ++r) {                 // t-side
        const int d = dt * 16 + w * 4 + r;
        const float4* wrow = (const float4*)(Wt + (size_t)d * 2048);
        float a0 = 0.0f, a1 = 0.0f;
        #pragma unroll
        for (int i = 0; i < 8; ++i) {
            const float4 wv = wrow[i * 64 + lane];
            a0 = dot4(wv, FT[i * 64 + lane], a0);
            a1 = dot4(wv, FT[512 + i * 64 + lane], a1);
        }
        a0 = wave_reduce64(a0) + bt[d];
        a1 = wave_reduce64(a1) + bt[d];
        pt0 = fmaf(a0, a0, pt0);
        pt1 = fmaf(a1, a1, pt1);
        if (lane == 0) {
            vraw_t[(size_t)b0 * 128 + d]       = a0;
            vraw_t[(size_t)(b0 + 1) * 128 + d] = a1;
        }
    }
    if (lane == 0) {
        atomicAdd(&n2s[b0],     ps0);
        atomicAdd(&n2s[b0 + 1], ps1);
        atomicAdd(&n2t[b0],     pt0);
        atomicAdd(&n2t[b0 + 1], pt1);
    }
}

// ---------------- bf16 MFMA GEMM -> S[b][row] (transposed, raw scale) --------
// LDS-free, barrier-free streaming GEMM. Each wave owns 16-row chunks of the
// bank (stride = total waves). V tile (64x128) lives in registers as 16 bf16
// MFMA fragments (64 VGPRs); A fragments are loaded register-direct from
// global with the exact lane->(row,k) mapping MFMA wants:
//   lane l: row = chunk0 + (l&15), k-block = (kk*4 + (l>>4))*8 .. +7
// f32 -> bf16 conversion in regs (same RNE as before -> identical numerics).
// No __syncthreads, no vmcnt(0) drain: ~8 independent 1KB loads in flight per
// wave, x ~12 waves/CU => HBM-BW-bound instead of latency-bound.
__global__ __launch_bounds__(256) void sgemm_kernel(
    const float* __restrict__ m1, const float* __restrict__ m2,
    const float* __restrict__ vraw_s, const float* __restrict__ vraw_t,
    float* __restrict__ S1, float* __restrict__ S2)
{
    const int t = threadIdx.x;
    const int bank = blockIdx.y;
    const float* __restrict__ bankp = bank ? m2 : m1;
    const float* __restrict__ vp    = bank ? vraw_s : vraw_t;
    float* __restrict__ Sp          = bank ? S2 : S1;

    const int lane = t & 63;
    const int m  = lane & 15;
    const int q4 = lane >> 4;

    // V fragments, register-resident: bf[n][kk] = bf16(V[n*16+m][(kk*4+q4)*8 .. +7])
    short8 bf[4][4];
    #pragma unroll
    for (int n = 0; n < 4; ++n) {
        const float4* vrow = (const float4*)(vp + (size_t)(n * 16 + m) * 128);
        #pragma unroll
        for (int kk = 0; kk < 4; ++kk) {
            const float4 lo = vrow[(kk * 4 + q4) * 2];
            const float4 hi = vrow[(kk * 4 + q4) * 2 + 1];
            bf[n][kk] = pack_bf16(lo, hi);
        }
    }

    const int wave   = (blockIdx.x << 2) | (t >> 6);
    const int nwaves = gridDim.x << 2;

    for (int cid = wave; cid < NCHUNKS; cid += nwaves) {
        const int row0 = cid << 4;
        const float4* arow = (const float4*)(bankp + (size_t)(row0 + m) * 128);

        float4 a[8];                               // 8 independent 16B loads
        #pragma unroll
        for (int kk = 0; kk < 4; ++kk) {
            a[kk * 2]     = arow[(kk * 4 + q4) * 2];
            a[kk * 2 + 1] = arow[(kk * 4 + q4) * 2 + 1];
        }
        short8 af[4];
        #pragma unroll
        for (int kk = 0; kk < 4; ++kk)
            af[kk] = pack_bf16(a[kk * 2], a[kk * 2 + 1]);

        const size_t cbase = (size_t)row0 + q4 * 4;
        #pragma unroll
        for (int n = 0; n < 4; ++n) {
            f32x4 acc = {0.f, 0.f, 0.f, 0.f};
            #pragma unroll
            for (int kk = 0; kk < 4; ++kk)
                acc = __builtin_amdgcn_mfma_f32_16x16x32_bf16(af[kk], bf[n][kk], acc, 0, 0, 0);
            // D frag: col(lane&15) = b = n*16+m, rows = q4*4 + 0..3
            *(f32x4*)(Sp + (size_t)(n * 16 + m) * NDATA + cbase) = acc;
        }
    }
}

// ---------------- gather negatives: accumulate sum(e), sum(e^2) only ---------
// grid (64 b-major, 16 parts): k = part*1024 + j*256 + t + 1 covers k=1..16384.
// 4 blocks/CU (was 2) -> 2x outstanding scattered loads for latency hiding.
__global__ __launch_bounds__(256) void gather_kernel(
    const int* __restrict__ cidx,
    const float* __restrict__ S1, const float* __restrict__ S2,
    const float* __restrict__ n2t, const float* __restrict__ n2s,
    float* __restrict__ acc)
{
    const int b = blockIdx.x, part = blockIdx.y, t = threadIdx.x;
    const float sct = INV_T * rsqrtf(n2t[b]);
    const float scs = INV_T * rsqrtf(n2s[b]);
    const float* __restrict__ S1b = S1 + (size_t)b * NDATA;
    const float* __restrict__ S2b = S2 + (size_t)b * NDATA;
    const int kbase = part * 1024 + 1;

    int rows[4];
    #pragma unroll
    for (int j = 0; j < 4; ++j)
        rows[j] = cidx[(size_t)b * KP1 + kbase + j * 256 + t];

    float v1[4], v2[4];
    #pragma unroll
    for (int j = 0; j < 4; ++j) {
        v1[j] = S1b[rows[j]];
        v2[j] = S2b[rows[j]];
    }

    float seT = 0.f, se2T = 0.f, seS = 0.f, se2S = 0.f;
    #pragma unroll
    for (int j = 0; j < 4; ++j) {
        const float e1 = __expf(v1[j] * sct);
        const float e2 = __expf(v2[j] * scs);
        seT += e1; se2T = fmaf(e1, e1, se2T);
        seS += e2; se2S = fmaf(e2, e2, se2S);
    }

    seT = wave_reduce64(seT);  se2T = wave_reduce64(se2T);
    seS = wave_reduce64(seS);  se2S = wave_reduce64(se2S);

    __shared__ float red[4][4];
    if ((t & 63) == 0) {
        const int w = t >> 6;
        red[w][0] = seT; red[w][1] = se2T; red[w][2] = seS; red[w][3] = se2S;
    }
    __syncthreads();
    if (t < 4)
        atomicAdd(&acc[t], red[0][t] + red[1][t] + red[2][t] + red[3][t]);
}

// ---------------- final: positives exact + closed-form negatives -------------
// Negatives: sum log(mPn/(x+c)) = (P-B)ln(mPn/c) - Su + Su2/2,
// Su = se_neg*invZ/c, Su2 = se2_neg*invZ^2/c^2 (u<=0.03 -> error <1e-3).
__global__ __launch_bounds__(64) void final_kernel(
    const int* __restrict__ idx,
    const float* __restrict__ S1, const float* __restrict__ S2,
    const float* __restrict__ n2t, const float* __restrict__ n2s,
    const float* __restrict__ acc, float* __restrict__ out)
{
    const int b = threadIdx.x;                 // 64 threads, one wave
    const float c = 0.16384f + 1e-7f;
    const int row = idx[b];

    const float e1p = __expf(S1[(size_t)b * NDATA + row] * INV_T * rsqrtf(n2t[b]));
    const float e2p = __expf(S2[(size_t)b * NDATA + row] * INV_T * rsqrtf(n2s[b]));

    const float pseT = wave_reduce64(e1p);
    const float pseS = wave_reduce64(e2p);

    const float seT_neg = acc[0], se2T_neg = acc[1];
    const float seS_neg = acc[2], se2S_neg = acc[3];

    const float zn = (float)PTOT / (float)NDATA;
    const float invZt = zn / (seT_neg + pseT);   // Z-sum includes positives
    const float invZs = zn / (seS_neg + pseS);

    const float PB = (float)(PTOT - BSZ);        // 1,048,576
    const float LOG_MPN_C = -6.1035156e-7f;      // ln(mPn / (mPn + 1e-7))
    const float ic = 1.0f / c;

    const float negT = PB * LOG_MPN_C
                     - seT_neg * invZt * ic
                     + 0.5f * se2T_neg * invZt * invZt * ic * ic;
    const float negS = PB * LOG_MPN_C
                     - seS_neg * invZs * ic
                     + 0.5f * se2S_neg * invZs * invZs * ic * ic;

    const float x0t = e1p * invZt, x0s = e2p * invZs;
    float pos = __logf(x0t / (x0t + c)) + __logf(x0s / (x0s + c));
    pos = wave_reduce64(pos);

    if (b == 0) out[0] = -(negT + negS + pos) * (1.0f / 64.0f);
}

extern "C" void kernel_launch(void* const* d_in, const int* in_sizes, int n_in,
                              void* d_out, int out_size, void* d_ws, size_t ws_size,
                              hipStream_t stream) {
    const float* fs   = (const float*)d_in[0];
    const float* ft   = (const float*)d_in[1];
    const int*   idx  = (const int*)d_in[2];
    const int*   cidx = (const int*)d_in[3];
    const float* Ws   = (const float*)d_in[4];
    const float* bs   = (const float*)d_in[5];
    const float* Wt   = (const float*)d_in[6];
    const float* bt   = (const float*)d_in[7];
    const float* m1   = (const float*)d_in[8];
    const float* m2   = (const float*)d_in[9];
    float* out = (float*)d_out;

    float* ws     = (float*)d_ws;
    float* n2t    = ws;                       // 64
    float* n2s    = ws + 64;                  // 64
    float* acc    = ws + 128;                 // 4 (+12 pad)
    float* vraw_s = ws + 144;                 // 8192
    float* vraw_t = vraw_s + 8192;            // 8192
    float* S1     = vraw_t + 8192;            // 64 x NDATA  [b][row]
    float* S2     = S1 + (size_t)BSZ * NDATA;

    hipMemsetAsync(ws, 0, 144 * sizeof(float), stream);   // n2t, n2s, acc

    embed_kernel<<<dim3(8, 32), dim3(256), 0, stream>>>(
        fs, ft, Ws, bs, Wt, bt, vraw_s, vraw_t, n2s, n2t);
    // 384x2 blocks = 3 blocks/CU co-resident (VGPR ~140 -> 3 waves/SIMD),
    // 3072 waves/bank, ~2 chunks/wave, strided so the access front stays dense.
    sgemm_kernel<<<dim3(384, 2), dim3(256), 0, stream>>>(
        m1, m2, vraw_s, vraw_t, S1, S2);
    gather_kernel<<<dim3(64, 16), dim3(256), 0, stream>>>(
        cidx, S1, S2, n2t, n2s, acc);
    final_kernel<<<dim3(1), dim3(64), 0, stream>>>(
        idx, S1, S2, n2t, n2s, acc, out);
}